// Round 6
// baseline (374.924 us; speedup 1.0000x reference)
//
#include <hip/hip_runtime.h>
#include <stdint.h>

#define N_ROWS 8192
#define IN_F   1024
#define OUT_F  1024
#define NG     5
#define KTOT   (IN_F * NG)  // 5120, k = g*1024 + i (g-major)

typedef float          f32x4 __attribute__((ext_vector_type(4)));
typedef short          s16x8 __attribute__((ext_vector_type(8)));
typedef unsigned short u16x8 __attribute__((ext_vector_type(8)));

__device__ __forceinline__ unsigned short f2bf_rne(float f) {
    unsigned u = __float_as_uint(f);
    u = (u + 0x7fffu + ((u >> 16) & 1u)) >> 16;
    return (unsigned short)u;
}
__device__ __forceinline__ float bf2f(unsigned short h) {
    return __uint_as_float(((unsigned)h) << 16);
}
__device__ __forceinline__ void gload_lds16(const void* g, void* l) {
    __builtin_amdgcn_global_load_lds(
        (const __attribute__((address_space(1))) unsigned int*)g,
        (__attribute__((address_space(3))) unsigned int*)l, 16, 0, 0);
}

// ================= PURE PATH (ws >= 180 MiB) =================
// prep_a: x -> hat-basis coeff planes Ah/Al bf16, layout [n][g*1024+i].
// c_g = max(0, 1-2|tanh(x)-gv|); split c = trunc-bf16 hi + trunc-bf16 lo.
__global__ __launch_bounds__(256) void prep_a(const float* __restrict__ x,
                                              unsigned short* __restrict__ Ahp,
                                              unsigned short* __restrict__ Alp) {
    int t = blockIdx.x * 256 + threadIdx.x;        // 1,048,576 threads x 8 elems
    int n = t >> 7, i8 = t & 127;
    const float4* xp = reinterpret_cast<const float4*>(x + (size_t)n * IN_F + i8 * 8);
    float4 a = xp[0], b = xp[1];
    float r[8] = {a.x, a.y, a.z, a.w, b.x, b.y, b.z, b.w};
    float xc[8];
#pragma unroll
    for (int j = 0; j < 8; ++j) {
        float v = fminf(fmaxf(r[j], -9.0f), 9.0f);
        float e = __expf(2.0f * v);
        xc[j] = (e - 1.0f) / (e + 1.0f);
    }
    size_t base = (size_t)n * KTOT + i8 * 8;
#pragma unroll
    for (int g = 0; g < NG; ++g) {
        float gv = -1.0f + 0.5f * (float)g;
        u16x8 hv, lv;
#pragma unroll
        for (int j = 0; j < 8; ++j) {
            float c  = fmaxf(0.0f, fmaf(-2.0f, fabsf(xc[j] - gv), 1.0f));
            unsigned hb = __float_as_uint(c) >> 16;            // trunc (c>=0)
            hv[j] = (unsigned short)hb;
            lv[j] = (unsigned short)(__float_as_uint(c - __uint_as_float(hb << 16)) >> 16);
        }
        *reinterpret_cast<u16x8*>(&Ahp[base + g * 1024]) = hv;
        *reinterpret_cast<u16x8*>(&Alp[base + g * 1024]) = lv;
    }
}

// prep_w: W[o][i][g] fp32 -> Wh/Wl bf16 planes [o][g*1024+i]
__global__ __launch_bounds__(256) void prep_w(const float* __restrict__ W,
                                              unsigned short* __restrict__ Wh,
                                              unsigned short* __restrict__ Wl) {
    int t  = blockIdx.x * 256 + threadIdx.x;
    int o  = t >> 8, i4 = (t & 255) * 4;
    const float4* wp = reinterpret_cast<const float4*>(W + (size_t)o * KTOT + i4 * NG);
    float f[20];
#pragma unroll
    for (int q = 0; q < 5; ++q) {
        float4 v = wp[q];
        f[q*4+0] = v.x; f[q*4+1] = v.y; f[q*4+2] = v.z; f[q*4+3] = v.w;
    }
#pragma unroll
    for (int g = 0; g < NG; ++g) {
        ushort4 hq, lq;
        unsigned short* hp = (unsigned short*)&hq;
        unsigned short* lp = (unsigned short*)&lq;
#pragma unroll
        for (int di = 0; di < 4; ++di) {
            float w = f[di * NG + g];
            unsigned short h = f2bf_rne(w);
            hp[di] = h;
            lp[di] = f2bf_rne(w - bf2f(h));
        }
        int dst = o * KTOT + g * 1024 + i4;
        *reinterpret_cast<ushort4*>(&Wh[dst]) = hq;
        *reinterpret_cast<ushort4*>(&Wl[dst]) = lq;
    }
}

// pure GEMM v2: 2-phase double-buffered (T3-min recipe), BK=32.
// LDS[buf][plane][row][slot]: elem = T[row][(slot ^ ((row>>1)&3))*8 + j].
// BK=32 swizzle note: row stride = 64B = 16 banks, so (row&1) supplies
// bank-half; XOR uses (row>>1)&3 -> per-16-lane read covers all 32 banks
// at 2-way (free, m136). Staging pre-swizzles the GLOBAL k-chunk (m173).
#define BM 128
#define BN 128
#define PBK 32
#define PNKT (KTOT / PBK)   // 160

struct SLdsDB { unsigned short d[2][4][BM * PBK]; };   // 65536 B -> 2 blk/CU

__global__ __launch_bounds__(256, 2) void kan_gemm_pure(
        const unsigned short* __restrict__ Ahp,
        const unsigned short* __restrict__ Alp,
        const unsigned short* __restrict__ Wh,
        const unsigned short* __restrict__ Wl,
        float* __restrict__ out) {
    __shared__ SLdsDB s;

    int bid = blockIdx.x;                       // 512 = 8 XCD x 64 (bijective)
    int wg  = (bid & 7) * 64 + (bid >> 3);
    int nb  = wg >> 6;                          // o-panel 0..7 (2.6MB L2-res)
    int mb  = wg & 63;
    int n0 = mb * BM, o0 = nb * BN;

    int tid  = threadIdx.x;
    int lane = tid & 63, wid = tid >> 6;
    int wm = wid >> 1, wn = wid & 1;

    // staging: per gload, lane l -> row (l>>2), slot (l&3); global k-chunk
    // pre-swizzled: ks = (l&3) ^ ((l>>3)&3)  [= slot ^ ((row>>1)&3)]
    int ks = (lane & 3) ^ ((lane >> 3) & 3);
    int gA[2], gB[2], ldsb[2];
#pragma unroll
    for (int q = 0; q < 2; ++q) {
        int r = wid * 32 + q * 16 + (lane >> 2);
        gA[q] = (n0 + r) * KTOT + ks * 8;
        gB[q] = (o0 + r) * KTOT + ks * 8;
        ldsb[q] = (wid * 32 + q * 16) * PBK;    // wave-uniform LDS base
    }
    // fragment reads: verified 16x16x32 mapping (R3 green): row=lane&15,
    // k-chunk = lane>>4; slot = chunk ^ ((row>>1)&3); invariant over m/nf.
    int sl0  = lane >> 4;
    int arow = wm * 64 + (lane & 15);
    int brow = wn * 64 + (lane & 15);
    int aaddr = arow * PBK + ((sl0 ^ ((arow >> 1) & 3)) << 3);  // + m*512
    int baddr = brow * PBK + ((sl0 ^ ((brow >> 1) & 3)) << 3);  // + nf*512

    f32x4 acc[4][4] = {};

    auto STAGE = [&](int buf, int k0) {
#pragma unroll
        for (int q = 0; q < 2; ++q) {
            gload_lds16(Ahp + gA[q] + k0, &s.d[buf][0][ldsb[q]]);
            gload_lds16(Alp + gA[q] + k0, &s.d[buf][1][ldsb[q]]);
            gload_lds16(Wh  + gB[q] + k0, &s.d[buf][2][ldsb[q]]);
            gload_lds16(Wl  + gB[q] + k0, &s.d[buf][3][ldsb[q]]);
        }
    };
    auto COMPUTE = [&](int buf) {
        s16x8 ah[4], al[4], bh[4], bl[4];
#pragma unroll
        for (int m = 0; m < 4; ++m) {
            ah[m] = *reinterpret_cast<const s16x8*>(&s.d[buf][0][aaddr + m * 512]);
            al[m] = *reinterpret_cast<const s16x8*>(&s.d[buf][1][aaddr + m * 512]);
        }
#pragma unroll
        for (int nf = 0; nf < 4; ++nf) {
            bh[nf] = *reinterpret_cast<const s16x8*>(&s.d[buf][2][baddr + nf * 512]);
            bl[nf] = *reinterpret_cast<const s16x8*>(&s.d[buf][3][baddr + nf * 512]);
        }
#pragma unroll
        for (int m = 0; m < 4; ++m)
#pragma unroll
            for (int nf = 0; nf < 4; ++nf) {
                acc[m][nf] = __builtin_amdgcn_mfma_f32_16x16x32_bf16(
                                 ah[m], bh[nf], acc[m][nf], 0, 0, 0);
                acc[m][nf] = __builtin_amdgcn_mfma_f32_16x16x32_bf16(
                                 ah[m], bl[nf], acc[m][nf], 0, 0, 0);
                acc[m][nf] = __builtin_amdgcn_mfma_f32_16x16x32_bf16(
                                 al[m], bh[nf], acc[m][nf], 0, 0, 0);
            }
    };

    // 2-phase pipeline: one barrier per K-step; compiler's vmcnt(0)+lgkmcnt(0)
    // before s_barrier (m97 asm) = the recipe's drain. Barrier also closes the
    // write-after-read hazard on the buffer being re-staged next iteration.
    STAGE(0, 0);
    __syncthreads();
    int cur = 0;
    for (int kt = 0; kt < PNKT - 1; ++kt) {
        STAGE(cur ^ 1, (kt + 1) * PBK);   // issue next tile (async, in flight)
        COMPUTE(cur);                     // latency hidden under this
        __syncthreads();
        cur ^= 1;
    }
    COMPUTE(cur);                         // last tile, no prefetch

    // epilogue: C/D col=lane&15, row=(lane>>4)*4+reg (R3-verified)
    int rb = n0 + wm * 64 + (lane >> 4) * 4;
    int cb = o0 + wn * 64 + (lane & 15);
#pragma unroll
    for (int m = 0; m < 4; ++m)
#pragma unroll
        for (int nf = 0; nf < 4; ++nf)
#pragma unroll
            for (int jj = 0; jj < 4; ++jj)
                out[(size_t)(rb + m * 16 + jj) * OUT_F + cb + nf * 16] =
                    acc[m][nf][jj];
}

// ================= MID PATH (36 MB <= ws < 180 MiB): audited R4 kernel =====
__global__ __launch_bounds__(256) void prep_p(const float* __restrict__ x,
                                              unsigned short* __restrict__ P) {
    int t = blockIdx.x * 256 + threadIdx.x;
    float4 a = reinterpret_cast<const float4*>(x)[t * 2];
    float4 b = reinterpret_cast<const float4*>(x)[t * 2 + 1];
    float r[8] = {a.x, a.y, a.z, a.w, b.x, b.y, b.z, b.w};
    u16x8 o;
#pragma unroll
    for (int j = 0; j < 8; ++j) {
        float xc = fminf(fmaxf(r[j], -9.0f), 9.0f);
        float e  = __expf(2.0f * xc);
        float th = (e - 1.0f) / (e + 1.0f);
        o[j] = (unsigned short)__float2uint_rn((th + 1.0f) * 32767.0f);
    }
    *reinterpret_cast<u16x8*>(&P[(size_t)t * 8]) = o;
}

#define MBM 64
#define MBN 256
#define MBK 32
struct SLdsM {
    unsigned short Ah[4 * MBM * 8];
    unsigned short Al[4 * MBM * 8];
    unsigned short Bh[4 * MBN * 8];
    unsigned short Bl[4 * MBN * 8];
};                                   // 40960 B -> 3 blocks/CU

__global__ __launch_bounds__(256, 3) void kan_gemm_mid(
        const unsigned short* __restrict__ P,
        const unsigned short* __restrict__ Wh,
        const unsigned short* __restrict__ Wl,
        float* __restrict__ out) {
    __shared__ SLdsM s;
    int bid = blockIdx.x;
    int wg  = (bid & 7) * 64 + (bid >> 3);
    int nb  = wg >> 7, mb = wg & 127;
    int n0 = mb * MBM, o0 = nb * MBN;
    int tid  = threadIdx.x;
    int lane = tid & 63, w = tid >> 6;

    int arow = tid >> 2, aks = tid & 3;
    int agoff = (n0 + arow) * IN_F + aks * 8;
    int aldst = aks * (MBM * 8) + arow * 8;
    int brow4 = tid >> 2, bchunk = tid & 3;
    int bldst = bchunk * (MBN * 8) + brow4 * 8;
    int bgq[4];
#pragma unroll
    for (int q = 0; q < 4; ++q)
        bgq[q] = (o0 + q * 64 + brow4) * KTOT + bchunk * 8;
    int fchunk = lane >> 4, fr = lane & 15;

    f32x4 acc[4][4] = {};
    for (int kt = 0; kt < KTOT / MBK; ++kt) {
        int k0 = kt * MBK;
        float gv = -1.0f + 0.5f * (float)(kt >> 5);
        int i0 = (kt & 31) * MBK;
        __syncthreads();
        u16x8 bregh[4], bregl[4];
#pragma unroll
        for (int q = 0; q < 4; ++q)
            bregh[q] = *reinterpret_cast<const u16x8*>(&Wh[bgq[q] + k0]);
#pragma unroll
        for (int q = 0; q < 4; ++q)
            bregl[q] = *reinterpret_cast<const u16x8*>(&Wl[bgq[q] + k0]);
        {
            u16x8 u = *reinterpret_cast<const u16x8*>(&P[agoff + i0]);
            u16x8 hv, lv;
#pragma unroll
            for (int j = 0; j < 8; ++j) {
                float xc = fmaf((float)u[j], (1.0f / 32767.0f), -1.0f);
                float c  = fmaxf(0.0f, fmaf(-2.0f, fabsf(xc - gv), 1.0f));
                unsigned hb = __float_as_uint(c) >> 16;
                hv[j] = (unsigned short)hb;
                lv[j] = (unsigned short)(__float_as_uint(c - __uint_as_float(hb << 16)) >> 16);
            }
            *reinterpret_cast<u16x8*>(&s.Ah[aldst]) = hv;
            *reinterpret_cast<u16x8*>(&s.Al[aldst]) = lv;
        }
#pragma unroll
        for (int q = 0; q < 4; ++q) {
            *reinterpret_cast<u16x8*>(&s.Bh[bldst + q * 512]) = bregh[q];
            *reinterpret_cast<u16x8*>(&s.Bl[bldst + q * 512]) = bregl[q];
        }
        __syncthreads();

        s16x8 ah[4], al[4], bh[4], bl[4];
#pragma unroll
        for (int m = 0; m < 4; ++m) {
            int e = fchunk * (MBM * 8) + (m * 16 + fr) * 8;
            ah[m] = *reinterpret_cast<const s16x8*>(&s.Ah[e]);
            al[m] = *reinterpret_cast<const s16x8*>(&s.Al[e]);
        }
#pragma unroll
        for (int nf = 0; nf < 4; ++nf) {
            int e = fchunk * (MBN * 8) + (w * 64 + nf * 16 + fr) * 8;
            bh[nf] = *reinterpret_cast<const s16x8*>(&s.Bh[e]);
            bl[nf] = *reinterpret_cast<const s16x8*>(&s.Bl[e]);
        }
#pragma unroll
        for (int m = 0; m < 4; ++m)
#pragma unroll
            for (int nf = 0; nf < 4; ++nf) {
                acc[m][nf] = __builtin_amdgcn_mfma_f32_16x16x32_bf16(
                                 ah[m], bh[nf], acc[m][nf], 0, 0, 0);
                acc[m][nf] = __builtin_amdgcn_mfma_f32_16x16x32_bf16(
                                 ah[m], bl[nf], acc[m][nf], 0, 0, 0);
                acc[m][nf] = __builtin_amdgcn_mfma_f32_16x16x32_bf16(
                                 al[m], bh[nf], acc[m][nf], 0, 0, 0);
            }
    }
    int rb = n0 + (lane >> 4) * 4;
    int cb = o0 + w * 64 + (lane & 15);
#pragma unroll
    for (int m = 0; m < 4; ++m)
#pragma unroll
        for (int nf = 0; nf < 4; ++nf)
#pragma unroll
            for (int jj = 0; jj < 4; ++jj)
                out[(size_t)(rb + m * 16 + jj) * OUT_F + cb + nf * 16] =
                    acc[m][nf][jj];
}

// ================= naive fallback =================
__global__ __launch_bounds__(256) void kan_naive(const float* __restrict__ x,
                                                 const float* __restrict__ W,
                                                 float* __restrict__ out) {
    int bn = blockIdx.x & 3;
    int bm = blockIdx.x >> 2;
    int o = bn * 256 + threadIdx.x;
    int nbase = bm * 16;
    float acc[16];
#pragma unroll
    for (int j = 0; j < 16; ++j) acc[j] = 0.0f;
    for (int i = 0; i < IN_F; ++i) {
        const float* wp = &W[(size_t)o * KTOT + i * NG];
        float w0 = wp[0], w1 = wp[1], w2 = wp[2], w3 = wp[3], w4 = wp[4];
#pragma unroll
        for (int j = 0; j < 16; ++j) {
            float xc = tanhf(x[(size_t)(nbase + j) * IN_F + i]);
            float c0 = fmaxf(0.f, fmaf(-2.f, fabsf(xc + 1.0f), 1.f));
            float c1 = fmaxf(0.f, fmaf(-2.f, fabsf(xc + 0.5f), 1.f));
            float c2 = fmaxf(0.f, fmaf(-2.f, fabsf(xc), 1.f));
            float c3 = fmaxf(0.f, fmaf(-2.f, fabsf(xc - 0.5f), 1.f));
            float c4 = fmaxf(0.f, fmaf(-2.f, fabsf(xc - 1.0f), 1.f));
            acc[j] += c0 * w0 + c1 * w1 + c2 * w2 + c3 * w3 + c4 * w4;
        }
    }
#pragma unroll
    for (int j = 0; j < 16; ++j)
        out[(size_t)(nbase + j) * OUT_F + o] = acc[j];
}

extern "C" void kernel_launch(void* const* d_in, const int* in_sizes, int n_in,
                              void* d_out, int out_size, void* d_ws, size_t ws_size,
                              hipStream_t stream) {
    const float* x = (const float*)d_in[0];
    const float* W = (const float*)d_in[1];
    float* out = (float*)d_out;

    const size_t APLANE  = (size_t)N_ROWS * KTOT * 2;      // 80 MiB
    const size_t WPLANE  = (size_t)OUT_F * KTOT * 2;       // 10 MiB
    const size_t P_BYTES = (size_t)N_ROWS * IN_F * 2;      // 16 MiB

    if (ws_size >= 2 * APLANE + 2 * WPLANE) {
        unsigned short* Ahp = (unsigned short*)d_ws;
        unsigned short* Alp = (unsigned short*)((char*)d_ws + APLANE);
        unsigned short* Wh  = (unsigned short*)((char*)d_ws + 2 * APLANE);
        unsigned short* Wl  = (unsigned short*)((char*)d_ws + 2 * APLANE + WPLANE);
        prep_a<<<(N_ROWS * IN_F / 8) / 256, 256, 0, stream>>>(x, Ahp, Alp);
        prep_w<<<(OUT_F * IN_F / 4) / 256, 256, 0, stream>>>(W, Wh, Wl);
        kan_gemm_pure<<<512, 256, 0, stream>>>(Ahp, Alp, Wh, Wl, out);
    } else if (ws_size >= P_BYTES + 2 * WPLANE) {
        unsigned short* P  = (unsigned short*)d_ws;
        unsigned short* Wh = (unsigned short*)((char*)d_ws + P_BYTES);
        unsigned short* Wl = (unsigned short*)((char*)d_ws + P_BYTES + WPLANE);
        prep_p<<<(N_ROWS * IN_F / 8) / 256, 256, 0, stream>>>(x, P);
        prep_w<<<(OUT_F * IN_F / 4) / 256, 256, 0, stream>>>(W, Wh, Wl);
        kan_gemm_mid<<<512, 256, 0, stream>>>(P, Wh, Wl, out);
    } else {
        kan_naive<<<2048, 256, 0, stream>>>(x, W, out);
    }
}